// Round 5
// baseline (558.692 us; speedup 1.0000x reference)
//
#include <hip/hip_runtime.h>
#include <hip/hip_bf16.h>
#include <math.h>

// B=2, S=2048, D=2048, H=16, KV=4, HD=128, n_rep=4
// qkv_tmp layout per row (b*2048+s): [0,2048) q | [2048,2560) k  (v goes straight to vt)
// wqkv is column-PERMUTED for q/k heads: head-local col c holds orig d = (c>>1)+((c&1)<<6)
// Q is scaled by (1/sqrt(128))*log2(e): flash softmax runs in exp2 domain.

typedef __attribute__((ext_vector_type(4))) float f32x4;
typedef __attribute__((ext_vector_type(8))) short short8;
typedef __attribute__((ext_vector_type(4))) unsigned short u16x4;
typedef __attribute__((ext_vector_type(8))) unsigned short u16x8;

static __device__ __forceinline__ unsigned short f2bf(float x) {
    unsigned u = __builtin_bit_cast(unsigned, x);
    u += 0x7fffu + ((u >> 16) & 1u);          // RNE
    return (unsigned short)(u >> 16);
}
static __device__ __forceinline__ float bf2f(unsigned short h) {
    unsigned u = ((unsigned)h) << 16;
    return __builtin_bit_cast(float, u);
}
static __device__ __forceinline__ float exp2_fast(float x) {
    float r;
    asm volatile("v_exp_f32 %0, %1" : "=v"(r) : "v"(x));
    return r;
}
static __device__ __forceinline__ unsigned cvt_pk_bf16(float a, float b) {
    unsigned r;                                // low16 = bf16(a), high16 = bf16(b)
    asm("v_cvt_pk_bf16_f32 %0, %1, %2" : "=v"(r) : "v"(a), "v"(b));
    return r;
}
static __device__ __forceinline__ void gload16(const unsigned short* g, unsigned short* lds) {
    __builtin_amdgcn_global_load_lds((const __attribute__((address_space(1))) void*)g,
                                     (__attribute__((address_space(3))) void*)lds, 16, 0, 0);
}

// ---------------- f32 -> bf16 conversion (vectorized) ----------------
__global__ __launch_bounds__(256) void k_conv(const float* __restrict__ src,
                                              unsigned short* __restrict__ dst, int n4) {
    int i = blockIdx.x * 256 + threadIdx.x;
    if (i >= n4) return;
    f32x4 v = ((const f32x4*)src)[i];
    u16x4 o;
    o.x = f2bf(v.x); o.y = f2bf(v.y); o.z = f2bf(v.z); o.w = f2bf(v.w);
    ((u16x4*)dst)[i] = o;
}

// concat wq(2048 rows) | wk(512) -> PERMUTED | wv(512) identity -> wqkv_bf16 [3072][2048]
__global__ __launch_bounds__(256) void k_conv_wqkv(const float* __restrict__ wq,
                                                   const float* __restrict__ wk,
                                                   const float* __restrict__ wv,
                                                   unsigned short* __restrict__ dst) {
    int i = blockIdx.x * 256 + threadIdx.x;     // chunk of 4 elems; 1,572,864 total
    long flat = (long)i * 4;
    int row = (int)(flat >> 11);
    int col = (int)(flat & 2047);
    const float* src;
    if (row < 2560) {                           // q or k: interleave pairs (d, d+64)
        int base = row & 2047;                  // q: row, k: row-2048
        int hh = base >> 7, ii = base & 127;
        int d = (ii >> 1) + ((ii & 1) << 6);
        src = (row < 2048 ? wq : wk) + (size_t)(hh * 128 + d) * 2048;
    } else {
        src = wv + (size_t)(row - 2560) * 2048;
    }
    f32x4 v = *(const f32x4*)(src + col);
    u16x4 o;
    o.x = f2bf(v.x); o.y = f2bf(v.y); o.z = f2bf(v.z); o.w = f2bf(v.w);
    *(u16x4*)(dst + flat) = o;
}

// ---------------- RoPE cos/sin table: [B*S][64] float2 ----------------
__global__ void k_rope_table(const int* __restrict__ pos_ids, float2* __restrict__ tb) {
    int r = blockIdx.x;            // 0..4095
    int i = threadIdx.x;           // 0..63
    float pos = (float)pos_ids[r];
    float powv = (float)pow(10000.0, (double)i / 64.0);
    float invf = 1.0f / powv;                       // mimic np f32 inv_freq
    float arg  = pos * invf;                        // f32 product like np
    double a = (double)arg;
    tb[(size_t)r * 64 + i] = make_float2((float)cos(a), (float)sin(a));
}

// ---------------- GEMM: C[M][N] = A[M][K] * W[N][K]^T  (bf16 in, f32 acc) ----------------
// 128x128 tile, BK=32, 4 waves (2x2), dbuf LDS + global_load_lds w16 + counted vmcnt.
// EPI 0: f32 store (O-proj). EPI 1: fused QKV epilogue (RoPE q/k from permuted cols,
// V written transposed to vt).
template <int EPI>
__global__ __launch_bounds__(256) void k_gemm(const unsigned short* __restrict__ A,
                                              const unsigned short* __restrict__ W,
                                              float* __restrict__ Cf,
                                              unsigned short* __restrict__ qkvt,
                                              unsigned short* __restrict__ vtb,
                                              const float2* __restrict__ tb,
                                              int M, int N, int K) {
    __shared__ unsigned short As[2][4096];   // 128 rows x 32 shorts
    __shared__ unsigned short Ws[2][4096];
    const int tid = threadIdx.x;
    const int lane = tid & 63;
    const int w = tid >> 6;
    const int q = lane & 15, g = lane >> 4;
    const int wr = w >> 1, wc = w & 1;
    const long mbase = (long)blockIdx.y * 128;
    const long nbase = (long)blockIdx.x * 128;

    const unsigned short* gA[2];
    const unsigned short* gW[2];
    #pragma unroll
    for (int j = 0; j < 2; ++j) {
        int r = j * 64 + (tid >> 2);
        int slot = (tid & 3) ^ ((r >> 1) & 3);
        gA[j] = A + (size_t)(mbase + r) * K + slot * 8;
        gW[j] = W + (size_t)(nbase + r) * K + slot * 8;
    }
    const int sa = (g ^ ((q >> 1) & 3)) * 8;   // read slot offset (shorts)

    f32x4 acc[4][4];
    #pragma unroll
    for (int m = 0; m < 4; ++m)
        #pragma unroll
        for (int n = 0; n < 4; ++n) acc[m][n] = (f32x4){0.f, 0.f, 0.f, 0.f};

    auto STAGE = [&](int buf) {
        #pragma unroll
        for (int j = 0; j < 2; ++j) {
            gload16(gA[j], &As[buf][j * 2048 + w * 512]);
            gload16(gW[j], &Ws[buf][j * 2048 + w * 512]);
            gA[j] += 32; gW[j] += 32;
        }
    };

    const int nk = K >> 5;
    STAGE(0);
    int cur = 0;
    for (int t = 0; t < nk; ++t) {
        if (t) __builtin_amdgcn_s_barrier();            // prev buffer free
        if (t + 1 < nk) {
            STAGE(cur ^ 1);
            asm volatile("s_waitcnt vmcnt(4)" ::: "memory");   // this tile's loads done
        } else {
            asm volatile("s_waitcnt vmcnt(0)" ::: "memory");
        }
        __builtin_amdgcn_s_barrier();                   // tile visible to all waves

        short8 af[4], bfr[4];
        #pragma unroll
        for (int m = 0; m < 4; ++m) af[m] = *(const short8*)&As[cur][(wr * 64 + m * 16 + q) * 32 + sa];
        #pragma unroll
        for (int n = 0; n < 4; ++n) bfr[n] = *(const short8*)&Ws[cur][(wc * 64 + n * 16 + q) * 32 + sa];
        #pragma unroll
        for (int m = 0; m < 4; ++m)
            #pragma unroll
            for (int n = 0; n < 4; ++n)
                acc[m][n] = __builtin_amdgcn_mfma_f32_16x16x32_bf16(af[m], bfr[n], acc[m][n], 0, 0, 0);
        cur ^= 1;
    }

    if (EPI == 0) {
        #pragma unroll
        for (int m = 0; m < 4; ++m)
            #pragma unroll
            for (int n = 0; n < 4; ++n)
                #pragma unroll
                for (int rr = 0; rr < 4; ++rr) {
                    long row = mbase + wr * 64 + m * 16 + 4 * g + rr;
                    long col = nbase + wc * 64 + n * 16 + q;
                    Cf[row * N + col] = acc[m][n][rr];
                }
    } else {
        const int tile = blockIdx.x;
        if (tile >= 20) {
            // V tile -> vt[(b*4+kv)*128 + c][s], 4 consecutive s per store
            const int kv = tile - 20;
            #pragma unroll
            for (int m = 0; m < 4; ++m)
                #pragma unroll
                for (int n = 0; n < 4; ++n) {
                    int c = wc * 64 + n * 16 + q;
                    long r0 = mbase + wr * 64 + m * 16 + 4 * g;
                    int b = (int)(r0 >> 11), s0 = (int)(r0 & 2047);
                    u16x4 pk;
                    #pragma unroll
                    for (int rr = 0; rr < 4; ++rr) pk[rr] = f2bf(acc[m][n][rr]);
                    *(u16x4*)(vtb + (size_t)((b * 4 + kv) * 128 + c) * 2048 + s0) = pk;
                }
        } else {
            // q/k tile: RoPE from permuted cols; un-permute on store
            const float scale = (tile < 16) ? 0.12751744f : 1.0f;  // (1/sqrt(128))*log2e for q
            const float sgn = (q & 1) ? 1.f : -1.f;
            #pragma unroll
            for (int m = 0; m < 4; ++m)
                #pragma unroll
                for (int rr = 0; rr < 4; ++rr) {
                    long row = mbase + wr * 64 + m * 16 + 4 * g + rr;
                    #pragma unroll
                    for (int n = 0; n < 4; ++n) {
                        int c = wc * 64 + n * 16 + q;
                        float x = acc[m][n][rr];
                        float p = __shfl_xor(x, 1);
                        float2 cs = tb[row * 64 + (c >> 1)];
                        float y = (x * cs.x + sgn * (p * cs.y)) * scale;
                        int dorig = (c >> 1) + ((c & 1) << 6);
                        long col = (tile < 16) ? (tile * 128 + dorig)
                                               : (2048 + (tile - 16) * 128 + dorig);
                        qkvt[row * 3072 + col] = f2bf(y);
                    }
                }
        }
    }
}

// ---------------- Flash attention ----------------
// 512 blocks (one (b,kvh) per XCD), 4 waves x 32 queries, KVBLK=64, exp2-domain softmax.
// K LDS-staged (dbuf, gload_lds, XOR-swizzle); V read DIRECT from global (L2-resident,
// XCD-pinned) -> LDS 42KB -> 3 blocks/CU. cvt_pk P-packing, setprio around MFMA.
__global__ __launch_bounds__(256, 3) void k_flash(const unsigned short* __restrict__ qkv,
                                                  const unsigned short* __restrict__ vt,
                                                  unsigned short* __restrict__ aout) {
    __shared__ unsigned short Ks[2][8192];   // 64 keys x 128 hd, dbuf
    __shared__ unsigned short Plds[4][1152]; // per-wave 16 x 72
    const int wg = blockIdx.x;
    const int kvg = wg & 7;            // b*4+kvh -> pinned per XCD
    const int inner = wg >> 3;         // 0..63
    const int h_in = inner & 3;
    const int qt = inner >> 2;         // 0..15
    const int b = kvg >> 2, kvh = kvg & 3;
    const int h = kvh * 4 + h_in;
    const int tid = threadIdx.x;
    const int w = tid >> 6, lane = tid & 63;
    const int q = lane & 15, g = lane >> 4;
    const int qrow = qt * 128 + w * 32;

    short8 qf[2][4];
    #pragma unroll
    for (int u = 0; u < 2; ++u) {
        const unsigned short* Qp = qkv + (size_t)(b * 2048 + qrow + u * 16 + q) * 3072 + h * 128 + g * 8;
        #pragma unroll
        for (int t = 0; t < 4; ++t) qf[u][t] = *(const short8*)(Qp + t * 32);
    }

    const unsigned short* Kbase = qkv + (size_t)(b * 2048) * 3072 + 2048 + kvh * 128;
    const unsigned short* Vbase = vt + (size_t)((b * 4 + kvh) * 128) * 2048;
    const unsigned short* gK[4];
    #pragma unroll
    for (int i = 0; i < 4; ++i) {
        int rowK = w * 16 + i * 4 + (lane >> 4);
        gK[i] = Kbase + (size_t)rowK * 3072 + (((lane & 15) ^ (rowK & 7)) << 3);
    }
    // V direct-read base: row d = nf*16+q, key offset g*8 (+ t*32 + k0)
    const unsigned short* Vp = Vbase + (size_t)q * 2048 + g * 8;

    const int swz = (q & 7) << 3;
    int tcK[4];
    #pragma unroll
    for (int t = 0; t < 4; ++t) tcK[t] = (t * 32 + g * 8) ^ swz;

    unsigned short* Pw = Plds[w];

    float m_run[2] = {-INFINITY, -INFINITY};
    float l_run[2] = {0.f, 0.f};
    f32x4 o[2][8];
    #pragma unroll
    for (int u = 0; u < 2; ++u)
        #pragma unroll
        for (int nf = 0; nf < 8; ++nf) o[u][nf] = (f32x4){0.f, 0.f, 0.f, 0.f};

    auto STAGE = [&](int buf) {
        #pragma unroll
        for (int i = 0; i < 4; ++i) {
            gload16(gK[i], &Ks[buf][w * 2048 + i * 512]);
            gK[i] += 64 * 3072;
        }
    };

    STAGE(0);
    int cur = 0;
    for (int t0 = 0; t0 < 32; ++t0) {
        if (t0 > 0) __builtin_amdgcn_s_barrier();
        if (t0 + 1 < 32) {
            STAGE(cur ^ 1);
            asm volatile("s_waitcnt vmcnt(4)" ::: "memory");
        } else {
            asm volatile("s_waitcnt vmcnt(0)" ::: "memory");
        }
        __builtin_amdgcn_s_barrier();

        const unsigned short* Kt = Ks[cur];

        // ---- V fragments direct from global (L2-hit; latency hidden under QK+softmax) ----
        short8 vf[8][2];
        #pragma unroll
        for (int nf = 0; nf < 8; ++nf) {
            const unsigned short* vp = Vp + (size_t)nf * 16 * 2048 + t0 * 64;
            vf[nf][0] = *(const short8*)(vp);
            vf[nf][1] = *(const short8*)(vp + 32);
        }

        // ---- QK^T both groups ----
        f32x4 st[2][4];
        __builtin_amdgcn_s_setprio(1);
        #pragma unroll
        for (int ks = 0; ks < 4; ++ks) {
            f32x4 a0 = (f32x4){0.f, 0.f, 0.f, 0.f};
            f32x4 a1 = (f32x4){0.f, 0.f, 0.f, 0.f};
            int rb = (ks * 16 + q) * 128;
            #pragma unroll
            for (int t = 0; t < 4; ++t) {
                short8 kf = *(const short8*)&Kt[rb + tcK[t]];
                a0 = __builtin_amdgcn_mfma_f32_16x16x32_bf16(kf, qf[0][t], a0, 0, 0, 0);
                a1 = __builtin_amdgcn_mfma_f32_16x16x32_bf16(kf, qf[1][t], a1, 0, 0, 0);
            }
            st[0][ks] = a0; st[1][ks] = a1;
        }
        __builtin_amdgcn_s_setprio(0);

        // ---- per group: softmax then PV (PV(u0) overlaps softmax(u1)) ----
        #pragma unroll
        for (int u = 0; u < 2; ++u) {
            float mx = fmaxf(
                fmaxf(fmaxf(fmaxf(st[u][0][0], st[u][0][1]), fmaxf(st[u][0][2], st[u][0][3])),
                      fmaxf(fmaxf(st[u][1][0], st[u][1][1]), fmaxf(st[u][1][2], st[u][1][3]))),
                fmaxf(fmaxf(fmaxf(st[u][2][0], st[u][2][1]), fmaxf(st[u][2][2], st[u][2][3])),
                      fmaxf(fmaxf(st[u][3][0], st[u][3][1]), fmaxf(st[u][3][2], st[u][3][3]))));
            mx = fmaxf(mx, __shfl_xor(mx, 16));
            mx = fmaxf(mx, __shfl_xor(mx, 32));
            if (__any(mx - m_run[u] > 8.0f)) {          // defer-max (exp2 domain)
                float mn = fmaxf(m_run[u], mx);
                float sc = exp2_fast(m_run[u] - mn);
                l_run[u] *= sc;
                f32x4 sv;
                #pragma unroll
                for (int rr = 0; rr < 4; ++rr) sv[rr] = __shfl(sc, 4 * g + rr);
                #pragma unroll
                for (int nf = 0; nf < 8; ++nf) o[u][nf] *= sv;
                m_run[u] = mn;
            }
            f32x4 pe[4];
            #pragma unroll
            for (int ks = 0; ks < 4; ++ks)
                #pragma unroll
                for (int rr = 0; rr < 4; ++rr) pe[ks][rr] = exp2_fast(st[u][ks][rr] - m_run[u]);
            f32x4 ls4 = (pe[0] + pe[1]) + (pe[2] + pe[3]);
            float ls = (ls4[0] + ls4[1]) + (ls4[2] + ls4[3]);
            ls += __shfl_xor(ls, 16);
            ls += __shfl_xor(ls, 32);
            l_run[u] += ls;

            #pragma unroll
            for (int ks = 0; ks < 4; ++ks) {
                uint2 pk;
                pk.x = cvt_pk_bf16(pe[ks][0], pe[ks][1]);
                pk.y = cvt_pk_bf16(pe[ks][2], pe[ks][3]);
                *(uint2*)&Pw[q * 72 + ks * 16 + 4 * g] = pk;
            }
            asm volatile("s_waitcnt lgkmcnt(0)" ::: "memory");
            short8 pa0 = *(const short8*)&Pw[q * 72 + g * 8];
            short8 pa1 = *(const short8*)&Pw[q * 72 + 32 + g * 8];

            __builtin_amdgcn_s_setprio(1);
            #pragma unroll
            for (int nf = 0; nf < 8; ++nf) {
                f32x4 a = o[u][nf];
                a = __builtin_amdgcn_mfma_f32_16x16x32_bf16(pa0, vf[nf][0], a, 0, 0, 0);
                a = __builtin_amdgcn_mfma_f32_16x16x32_bf16(pa1, vf[nf][1], a, 0, 0, 0);
                o[u][nf] = a;
            }
            __builtin_amdgcn_s_setprio(0);
        }
        cur ^= 1;
    }

    #pragma unroll
    for (int u = 0; u < 2; ++u) {
        f32x4 li, li_inv;
        #pragma unroll
        for (int rr = 0; rr < 4; ++rr) li[rr] = __shfl(l_run[u], 4 * g + rr);
        #pragma unroll
        for (int rr = 0; rr < 4; ++rr) li_inv[rr] = 1.0f / li[rr];
        #pragma unroll
        for (int nf = 0; nf < 8; ++nf)
            #pragma unroll
            for (int rr = 0; rr < 4; ++rr) {
                size_t row = (size_t)(b * 2048 + qrow + u * 16 + 4 * g + rr);
                aout[row * 2048 + h * 128 + nf * 16 + q] = f2bf(o[u][nf][rr] * li_inv[rr]);
            }
    }
}

extern "C" void kernel_launch(void* const* d_in, const int* in_sizes, int n_in,
                              void* d_out, int out_size, void* d_ws, size_t ws_size,
                              hipStream_t stream) {
    (void)in_sizes; (void)n_in; (void)out_size; (void)ws_size;
    const float* hs = (const float*)d_in[0];
    const int* pos  = (const int*)d_in[1];
    const float* wq = (const float*)d_in[2];
    const float* wk = (const float*)d_in[3];
    const float* wv = (const float*)d_in[4];
    const float* wo = (const float*)d_in[5];
    float* out = (float*)d_out;

    unsigned short* hsb   = (unsigned short*)d_ws;              // 4096*2048
    unsigned short* wqkvb = hsb + (size_t)4096 * 2048;          // 3072*2048
    unsigned short* wob   = wqkvb + (size_t)3072 * 2048;        // 2048*2048
    unsigned short* qkvt  = wob + (size_t)2048 * 2048;          // 4096*3072 (q|k used)
    unsigned short* vtb   = qkvt + (size_t)4096 * 3072;         // 8*128*2048
    float2* tb            = (float2*)(vtb + (size_t)8 * 128 * 2048);   // 4096*64
    unsigned short* aoutb = (unsigned short*)(tb + (size_t)4096 * 64); // 4096*2048

    k_conv<<<8192, 256, 0, stream>>>(hs, hsb, 2097152);
    k_conv_wqkv<<<6144, 256, 0, stream>>>(wq, wk, wv, wqkvb);
    k_conv<<<4096, 256, 0, stream>>>(wo, wob, 1048576);
    k_rope_table<<<4096, 64, 0, stream>>>(pos, tb);
    k_gemm<1><<<dim3(24, 32), 256, 0, stream>>>(hsb, wqkvb, nullptr, qkvt, vtb, tb, 4096, 3072, 2048);
    k_flash<<<dim3(512), 256, 0, stream>>>(qkvt, vtb, aoutb);
    k_gemm<0><<<dim3(16, 32), 256, 0, stream>>>(aoutb, wob, out, nullptr, nullptr, nullptr, 4096, 2048, 2048);
}

// Round 6
// 226.532 us; speedup vs baseline: 2.4663x; 2.4663x over previous
//
#include <hip/hip_runtime.h>
#include <hip/hip_bf16.h>
#include <math.h>

// B=2, S=2048, D=2048, H=16, KV=4, HD=128, n_rep=4
// qkv_tmp layout per row (b*2048+s): [0,2048) q | [2048,2560) k  (v goes straight to vt)
// wqkv is column-PERMUTED for q/k heads: head-local col c holds orig d = (c>>1)+((c&1)<<6)
// Q is scaled by (1/sqrt(128))*log2(e): flash softmax runs in exp2 domain.

typedef __attribute__((ext_vector_type(4))) float f32x4;
typedef __attribute__((ext_vector_type(8))) short short8;
typedef __attribute__((ext_vector_type(4))) unsigned short u16x4;
typedef __attribute__((ext_vector_type(8))) unsigned short u16x8;

static __device__ __forceinline__ unsigned short f2bf(float x) {
    unsigned u = __builtin_bit_cast(unsigned, x);
    u += 0x7fffu + ((u >> 16) & 1u);          // RNE
    return (unsigned short)(u >> 16);
}
static __device__ __forceinline__ float bf2f(unsigned short h) {
    unsigned u = ((unsigned)h) << 16;
    return __builtin_bit_cast(float, u);
}
static __device__ __forceinline__ float exp2_fast(float x) {
    float r;
    asm volatile("v_exp_f32 %0, %1" : "=v"(r) : "v"(x));
    return r;
}
static __device__ __forceinline__ void gload16(const unsigned short* g, unsigned short* lds) {
    __builtin_amdgcn_global_load_lds((const __attribute__((address_space(1))) void*)g,
                                     (__attribute__((address_space(3))) void*)lds, 16, 0, 0);
}

// ---------------- fused prep: hs->bf16 | wqkv permuted concat | wo->bf16 | rope table ----
// items: [0,2097152) hs x4 | [2097152,3670016) wqkv x4 | [3670016,4718592) wo x4
//        | [4718592,4980736) rope entries
__global__ __launch_bounds__(256) void k_prep(const float* __restrict__ hs,
                                              const float* __restrict__ wq,
                                              const float* __restrict__ wk,
                                              const float* __restrict__ wv,
                                              const float* __restrict__ wo,
                                              const int* __restrict__ pos_ids,
                                              unsigned short* __restrict__ hsb,
                                              unsigned short* __restrict__ wqkvb,
                                              unsigned short* __restrict__ wob,
                                              float2* __restrict__ tb) {
    long idx = (long)blockIdx.x * 256 + threadIdx.x;
    if (idx < 2097152) {                       // hs -> bf16
        f32x4 v = ((const f32x4*)hs)[idx];
        u16x4 o;
        o.x = f2bf(v.x); o.y = f2bf(v.y); o.z = f2bf(v.z); o.w = f2bf(v.w);
        ((u16x4*)hsb)[idx] = o;
    } else if (idx < 3670016) {                // wqkv concat (q/k col-permuted)
        long i = idx - 2097152;
        long flat = i * 4;
        int row = (int)(flat >> 11);
        int col = (int)(flat & 2047);
        const float* src;
        if (row < 2560) {
            int base = row & 2047;
            int hh = base >> 7, ii = base & 127;
            int d = (ii >> 1) + ((ii & 1) << 6);
            src = (row < 2048 ? wq : wk) + (size_t)(hh * 128 + d) * 2048;
        } else {
            src = wv + (size_t)(row - 2560) * 2048;
        }
        f32x4 v = *(const f32x4*)(src + col);
        u16x4 o;
        o.x = f2bf(v.x); o.y = f2bf(v.y); o.z = f2bf(v.z); o.w = f2bf(v.w);
        *(u16x4*)(wqkvb + flat) = o;
    } else if (idx < 4718592) {                // wo -> bf16
        long i = idx - 3670016;
        f32x4 v = ((const f32x4*)wo)[i];
        u16x4 o;
        o.x = f2bf(v.x); o.y = f2bf(v.y); o.z = f2bf(v.z); o.w = f2bf(v.w);
        ((u16x4*)wob)[i] = o;
    } else {                                   // rope table
        long j = idx - 4718592;                // [0, 262144)
        int r = (int)(j >> 6);
        int i = (int)(j & 63);
        float pos = (float)pos_ids[r];
        float powv = (float)pow(10000.0, (double)i / 64.0);
        float invf = 1.0f / powv;
        float arg  = pos * invf;
        double a = (double)arg;
        tb[(size_t)r * 64 + i] = make_float2((float)cos(a), (float)sin(a));
    }
}

// ---------------- GEMM: C[M][N] = A[M][K] * W[N][K]^T  (bf16 in, f32 acc) ----------------
// 128x128 tile, BK=32, 4 waves (2x2), dbuf LDS + global_load_lds w16 + counted vmcnt.
// XCD-aware bijective block swizzle (grid size divisible by 8).
// EPI 0: f32 store (O-proj). EPI 1: fused QKV epilogue (RoPE q/k, V transposed to vt).
template <int EPI>
__global__ __launch_bounds__(256) void k_gemm(const unsigned short* __restrict__ A,
                                              const unsigned short* __restrict__ W,
                                              float* __restrict__ Cf,
                                              unsigned short* __restrict__ qkvt,
                                              unsigned short* __restrict__ vtb,
                                              const float2* __restrict__ tb,
                                              int M, int N, int K) {
    __shared__ unsigned short As[2][4096];   // 128 rows x 32 shorts
    __shared__ unsigned short Ws[2][4096];
    const int tid = threadIdx.x;
    const int lane = tid & 63;
    const int w = tid >> 6;
    const int q = lane & 15, g = lane >> 4;
    const int wr = w >> 1, wc = w & 1;

    // XCD swizzle (bijective: gridDim.x*gridDim.y % 8 == 0)
    const int nwg = gridDim.x * gridDim.y;
    const int id = blockIdx.y * gridDim.x + blockIdx.x;
    const int swz_id = (id & 7) * (nwg >> 3) + (id >> 3);
    const int bx = swz_id % gridDim.x;
    const int by = swz_id / gridDim.x;
    const long mbase = (long)by * 128;
    const long nbase = (long)bx * 128;

    const unsigned short* gA[2];
    const unsigned short* gW[2];
    #pragma unroll
    for (int j = 0; j < 2; ++j) {
        int r = j * 64 + (tid >> 2);
        int slot = (tid & 3) ^ ((r >> 1) & 3);
        gA[j] = A + (size_t)(mbase + r) * K + slot * 8;
        gW[j] = W + (size_t)(nbase + r) * K + slot * 8;
    }
    const int sa = (g ^ ((q >> 1) & 3)) * 8;   // read slot offset (shorts)

    f32x4 acc[4][4];
    #pragma unroll
    for (int m = 0; m < 4; ++m)
        #pragma unroll
        for (int n = 0; n < 4; ++n) acc[m][n] = (f32x4){0.f, 0.f, 0.f, 0.f};

    auto STAGE = [&](int buf) {
        #pragma unroll
        for (int j = 0; j < 2; ++j) {
            gload16(gA[j], &As[buf][j * 2048 + w * 512]);
            gload16(gW[j], &Ws[buf][j * 2048 + w * 512]);
            gA[j] += 32; gW[j] += 32;
        }
    };

    const int nk = K >> 5;
    STAGE(0);
    int cur = 0;
    for (int t = 0; t < nk; ++t) {
        if (t) __builtin_amdgcn_s_barrier();            // prev buffer free
        if (t + 1 < nk) {
            STAGE(cur ^ 1);
            asm volatile("s_waitcnt vmcnt(4)" ::: "memory");   // this tile's loads done
        } else {
            asm volatile("s_waitcnt vmcnt(0)" ::: "memory");
        }
        __builtin_amdgcn_s_barrier();                   // tile visible to all waves

        short8 af[4], bfr[4];
        #pragma unroll
        for (int m = 0; m < 4; ++m) af[m] = *(const short8*)&As[cur][(wr * 64 + m * 16 + q) * 32 + sa];
        #pragma unroll
        for (int n = 0; n < 4; ++n) bfr[n] = *(const short8*)&Ws[cur][(wc * 64 + n * 16 + q) * 32 + sa];
        #pragma unroll
        for (int m = 0; m < 4; ++m)
            #pragma unroll
            for (int n = 0; n < 4; ++n)
                acc[m][n] = __builtin_amdgcn_mfma_f32_16x16x32_bf16(af[m], bfr[n], acc[m][n], 0, 0, 0);
        cur ^= 1;
    }

    if (EPI == 0) {
        #pragma unroll
        for (int m = 0; m < 4; ++m)
            #pragma unroll
            for (int n = 0; n < 4; ++n)
                #pragma unroll
                for (int rr = 0; rr < 4; ++rr) {
                    long row = mbase + wr * 64 + m * 16 + 4 * g + rr;
                    long col = nbase + wc * 64 + n * 16 + q;
                    Cf[row * N + col] = acc[m][n][rr];
                }
    } else {
        const int tile = bx;
        if (tile >= 20) {
            // V tile -> vt[(b*4+kv)*128 + c][s], 4 consecutive s per store
            const int kv = tile - 20;
            #pragma unroll
            for (int m = 0; m < 4; ++m)
                #pragma unroll
                for (int n = 0; n < 4; ++n) {
                    int c = wc * 64 + n * 16 + q;
                    long r0 = mbase + wr * 64 + m * 16 + 4 * g;
                    int b = (int)(r0 >> 11), s0 = (int)(r0 & 2047);
                    u16x4 pk;
                    #pragma unroll
                    for (int rr = 0; rr < 4; ++rr) pk[rr] = f2bf(acc[m][n][rr]);
                    *(u16x4*)(vtb + (size_t)((b * 4 + kv) * 128 + c) * 2048 + s0) = pk;
                }
        } else {
            // q/k tile: RoPE from permuted cols; un-permute on store
            const float scale = (tile < 16) ? 0.12751744f : 1.0f;  // (1/sqrt(128))*log2e for q
            const float sgn = (q & 1) ? 1.f : -1.f;
            #pragma unroll
            for (int m = 0; m < 4; ++m)
                #pragma unroll
                for (int rr = 0; rr < 4; ++rr) {
                    long row = mbase + wr * 64 + m * 16 + 4 * g + rr;
                    #pragma unroll
                    for (int n = 0; n < 4; ++n) {
                        int c = wc * 64 + n * 16 + q;
                        float x = acc[m][n][rr];
                        float p = __shfl_xor(x, 1);
                        float2 cs = tb[row * 64 + (c >> 1)];
                        float y = (x * cs.x + sgn * (p * cs.y)) * scale;
                        int dorig = (c >> 1) + ((c & 1) << 6);
                        long col = (tile < 16) ? (tile * 128 + dorig)
                                               : (2048 + (tile - 16) * 128 + dorig);
                        qkvt[row * 3072 + col] = f2bf(y);
                    }
                }
        }
    }
}

// ---------------- Flash attention (known-good R4 config) ----------------
// 512 blocks (one (b,kvh) per XCD), 4 waves x 32 queries, KVBLK=64, exp2-domain softmax.
// K and V LDS-staged (dbuf, gload_lds, XOR-swizzle), counted vmcnt(8).
__global__ __launch_bounds__(256, 2) void k_flash(const unsigned short* __restrict__ qkv,
                                                  const unsigned short* __restrict__ vt,
                                                  unsigned short* __restrict__ aout) {
    __shared__ unsigned short Ks[2][8192];   // 64 keys x 128 hd, dbuf
    __shared__ unsigned short Vs[2][8192];   // 128 d x 64 keys, dbuf
    __shared__ unsigned short Plds[4][1152]; // per-wave 16 x 72
    const int wg = blockIdx.x;
    const int kvg = wg & 7;            // b*4+kvh -> pinned per XCD
    const int inner = wg >> 3;         // 0..63
    const int h_in = inner & 3;
    const int qt = inner >> 2;         // 0..15
    const int b = kvg >> 2, kvh = kvg & 3;
    const int h = kvh * 4 + h_in;
    const int tid = threadIdx.x;
    const int w = tid >> 6, lane = tid & 63;
    const int q = lane & 15, g = lane >> 4;
    const int qrow = qt * 128 + w * 32;

    short8 qf[2][4];
    #pragma unroll
    for (int u = 0; u < 2; ++u) {
        const unsigned short* Qp = qkv + (size_t)(b * 2048 + qrow + u * 16 + q) * 3072 + h * 128 + g * 8;
        #pragma unroll
        for (int t = 0; t < 4; ++t) qf[u][t] = *(const short8*)(Qp + t * 32);
    }

    const unsigned short* Kbase = qkv + (size_t)(b * 2048) * 3072 + 2048 + kvh * 128;
    const unsigned short* Vbase = vt + (size_t)((b * 4 + kvh) * 128) * 2048;
    const unsigned short* gK[4];
    const unsigned short* gV[4];
    #pragma unroll
    for (int i = 0; i < 4; ++i) {
        int rowK = w * 16 + i * 4 + (lane >> 4);
        gK[i] = Kbase + (size_t)rowK * 3072 + (((lane & 15) ^ (rowK & 7)) << 3);
        int rowV = w * 32 + i * 8 + (lane >> 3);
        gV[i] = Vbase + (size_t)rowV * 2048 + (((lane & 7) ^ (rowV & 7)) << 3);
    }

    const int swz = (q & 7) << 3;
    int tcK[4];
    #pragma unroll
    for (int t = 0; t < 4; ++t) tcK[t] = (t * 32 + g * 8) ^ swz;

    unsigned short* Pw = Plds[w];

    float m_run[2] = {-INFINITY, -INFINITY};
    float l_run[2] = {0.f, 0.f};
    f32x4 o[2][8];
    #pragma unroll
    for (int u = 0; u < 2; ++u)
        #pragma unroll
        for (int nf = 0; nf < 8; ++nf) o[u][nf] = (f32x4){0.f, 0.f, 0.f, 0.f};

    auto STAGE = [&](int buf) {
        #pragma unroll
        for (int i = 0; i < 4; ++i) {
            gload16(gK[i], &Ks[buf][w * 2048 + i * 512]);
            gload16(gV[i], &Vs[buf][w * 2048 + i * 512]);
            gK[i] += 64 * 3072;
            gV[i] += 64;
        }
    };

    STAGE(0);
    int cur = 0;
    for (int t0 = 0; t0 < 32; ++t0) {
        if (t0 > 0) __builtin_amdgcn_s_barrier();
        if (t0 + 1 < 32) {
            STAGE(cur ^ 1);
            asm volatile("s_waitcnt vmcnt(8)" ::: "memory");
        } else {
            asm volatile("s_waitcnt vmcnt(0)" ::: "memory");
        }
        __builtin_amdgcn_s_barrier();

        const unsigned short* Kt = Ks[cur];
        const unsigned short* Vt = Vs[cur];

        // ---- QK^T both groups ----
        f32x4 st[2][4];
        #pragma unroll
        for (int ks = 0; ks < 4; ++ks) {
            f32x4 a0 = (f32x4){0.f, 0.f, 0.f, 0.f};
            f32x4 a1 = (f32x4){0.f, 0.f, 0.f, 0.f};
            int rb = (ks * 16 + q) * 128;
            #pragma unroll
            for (int t = 0; t < 4; ++t) {
                short8 kf = *(const short8*)&Kt[rb + tcK[t]];
                a0 = __builtin_amdgcn_mfma_f32_16x16x32_bf16(kf, qf[0][t], a0, 0, 0, 0);
                a1 = __builtin_amdgcn_mfma_f32_16x16x32_bf16(kf, qf[1][t], a1, 0, 0, 0);
            }
            st[0][ks] = a0; st[1][ks] = a1;
        }

        // ---- V fragments to registers ----
        short8 vf[8][2];
        #pragma unroll
        for (int nf = 0; nf < 8; ++nf) {
            int rb = (nf * 16 + q) * 64;
            #pragma unroll
            for (int t = 0; t < 2; ++t) vf[nf][t] = *(const short8*)&Vt[rb + tcK[t]];
        }

        // ---- per group: softmax then PV (PV(u0) overlaps softmax(u1)) ----
        #pragma unroll
        for (int u = 0; u < 2; ++u) {
            float mx = fmaxf(
                fmaxf(fmaxf(fmaxf(st[u][0][0], st[u][0][1]), fmaxf(st[u][0][2], st[u][0][3])),
                      fmaxf(fmaxf(st[u][1][0], st[u][1][1]), fmaxf(st[u][1][2], st[u][1][3]))),
                fmaxf(fmaxf(fmaxf(st[u][2][0], st[u][2][1]), fmaxf(st[u][2][2], st[u][2][3])),
                      fmaxf(fmaxf(st[u][3][0], st[u][3][1]), fmaxf(st[u][3][2], st[u][3][3]))));
            mx = fmaxf(mx, __shfl_xor(mx, 16));
            mx = fmaxf(mx, __shfl_xor(mx, 32));
            if (__any(mx - m_run[u] > 8.0f)) {          // defer-max (exp2 domain)
                float mn = fmaxf(m_run[u], mx);
                float sc = exp2_fast(m_run[u] - mn);
                l_run[u] *= sc;
                f32x4 sv;
                #pragma unroll
                for (int rr = 0; rr < 4; ++rr) sv[rr] = __shfl(sc, 4 * g + rr);
                #pragma unroll
                for (int nf = 0; nf < 8; ++nf) o[u][nf] *= sv;
                m_run[u] = mn;
            }
            f32x4 pe[4];
            #pragma unroll
            for (int ks = 0; ks < 4; ++ks)
                #pragma unroll
                for (int rr = 0; rr < 4; ++rr) pe[ks][rr] = exp2_fast(st[u][ks][rr] - m_run[u]);
            f32x4 ls4 = (pe[0] + pe[1]) + (pe[2] + pe[3]);
            float ls = (ls4[0] + ls4[1]) + (ls4[2] + ls4[3]);
            ls += __shfl_xor(ls, 16);
            ls += __shfl_xor(ls, 32);
            l_run[u] += ls;

            #pragma unroll
            for (int ks = 0; ks < 4; ++ks) {
                u16x4 pk;
                #pragma unroll
                for (int rr = 0; rr < 4; ++rr) pk[rr] = f2bf(pe[ks][rr]);
                *(u16x4*)&Pw[q * 72 + ks * 16 + 4 * g] = pk;
            }
            asm volatile("s_waitcnt lgkmcnt(0)" ::: "memory");
            short8 pa0 = *(const short8*)&Pw[q * 72 + g * 8];
            short8 pa1 = *(const short8*)&Pw[q * 72 + 32 + g * 8];

            #pragma unroll
            for (int nf = 0; nf < 8; ++nf) {
                f32x4 a = o[u][nf];
                a = __builtin_amdgcn_mfma_f32_16x16x32_bf16(pa0, vf[nf][0], a, 0, 0, 0);
                a = __builtin_amdgcn_mfma_f32_16x16x32_bf16(pa1, vf[nf][1], a, 0, 0, 0);
                o[u][nf] = a;
            }
        }
        cur ^= 1;
    }

    #pragma unroll
    for (int u = 0; u < 2; ++u) {
        f32x4 li;
        #pragma unroll
        for (int rr = 0; rr < 4; ++rr) li[rr] = __shfl(l_run[u], 4 * g + rr);
        #pragma unroll
        for (int nf = 0; nf < 8; ++nf)
            #pragma unroll
            for (int rr = 0; rr < 4; ++rr) {
                size_t row = (size_t)(b * 2048 + qrow + u * 16 + 4 * g + rr);
                aout[row * 2048 + h * 128 + nf * 16 + q] = f2bf(o[u][nf][rr] / li[rr]);
            }
    }
}

extern "C" void kernel_launch(void* const* d_in, const int* in_sizes, int n_in,
                              void* d_out, int out_size, void* d_ws, size_t ws_size,
                              hipStream_t stream) {
    (void)in_sizes; (void)n_in; (void)out_size; (void)ws_size;
    const float* hs = (const float*)d_in[0];
    const int* pos  = (const int*)d_in[1];
    const float* wq = (const float*)d_in[2];
    const float* wk = (const float*)d_in[3];
    const float* wv = (const float*)d_in[4];
    const float* wo = (const float*)d_in[5];
    float* out = (float*)d_out;

    unsigned short* hsb   = (unsigned short*)d_ws;              // 4096*2048
    unsigned short* wqkvb = hsb + (size_t)4096 * 2048;          // 3072*2048
    unsigned short* wob   = wqkvb + (size_t)3072 * 2048;        // 2048*2048
    unsigned short* qkvt  = wob + (size_t)2048 * 2048;          // 4096*3072 (q|k used)
    unsigned short* vtb   = qkvt + (size_t)4096 * 3072;         // 8*128*2048
    float2* tb            = (float2*)(vtb + (size_t)8 * 128 * 2048);   // 4096*64
    unsigned short* aoutb = (unsigned short*)(tb + (size_t)4096 * 64); // 4096*2048

    k_prep<<<19456, 256, 0, stream>>>(hs, wq, wk, wv, wo, pos, hsb, wqkvb, wob, tb);
    k_gemm<1><<<dim3(24, 32), 256, 0, stream>>>(hsb, wqkvb, nullptr, qkvt, vtb, tb, 4096, 3072, 2048);
    k_flash<<<dim3(512), 256, 0, stream>>>(qkvt, vtb, aoutb);
    k_gemm<0><<<dim3(16, 32), 256, 0, stream>>>(aoutb, wob, out, nullptr, nullptr, nullptr, 4096, 2048, 2048);
}